// Round 2
// baseline (934.904 us; speedup 1.0000x reference)
//
#include <hip/hip_runtime.h>
#include <cstdint>
#include <cstddef>

#define NN 50000
#define NE 800000
#define DD 128

static_assert(NN % 16 == 0, "node tiles");
static_assert(NE % 16 == 0, "edge tiles");

typedef __bf16 bf16_t;
typedef bf16_t bf16x8 __attribute__((ext_vector_type(8)));
typedef bf16_t bf16x4 __attribute__((ext_vector_type(4)));
typedef float f32x4 __attribute__((ext_vector_type(4)));

__device__ __forceinline__ float gelu_f(float x) {
    return 0.5f * x * (1.0f + erff(x * 0.70710678118654752f));
}

// ---------------- feat f32 -> bf16 ----------------
__global__ __launch_bounds__(256) void convert_feat_kernel(
    const float* __restrict__ feat, bf16_t* __restrict__ fb)
{
    int i = blockIdx.x * 256 + threadIdx.x;  // quad index; NN*DD/4 = 1.6M exact
    f32x4 v = ((const f32x4*)feat)[i];
    bf16x4 o;
    o[0] = (bf16_t)v[0]; o[1] = (bf16_t)v[1]; o[2] = (bf16_t)v[2]; o[3] = (bf16_t)v[3];
    ((bf16x4*)fb)[i] = o;
}

// ---------------- prep: combine + convert weights, combine biases ----------------
__global__ __launch_bounds__(256) void prep_kernel(
    const float* __restrict__ W_asrc, const float* __restrict__ b_asrc,
    const float* __restrict__ W_adst, const float* __restrict__ b_adst,
    const float* __restrict__ W_asub, const float* __restrict__ b_asub,
    const float* __restrict__ W_amul, const float* __restrict__ b_amul,
    const float* __restrict__ W_pool, const float* __restrict__ W_pool2,
    const float* __restrict__ W_self, const float* __restrict__ b_self,
    const float* __restrict__ W_neigh, const float* __restrict__ b_neigh,
    const float* __restrict__ W_neigh2, const float* __restrict__ b_neigh2,
    const float* __restrict__ W_mlp,
    bf16_t* __restrict__ W_S, bf16_t* __restrict__ W_D, bf16_t* __restrict__ W_amulb,
    bf16_t* __restrict__ W_poolb, bf16_t* __restrict__ W_pool2b,
    bf16_t* __restrict__ W_selfb, bf16_t* __restrict__ W_neighb, bf16_t* __restrict__ W_neigh2b,
    bf16_t* __restrict__ W_mlpb,
    float* __restrict__ b_e, float* __restrict__ b_rst)
{
    int gid = blockIdx.x * 256 + threadIdx.x;  // 64 blocks * 256 = 16384 = DD*DD
    float sub = W_asub[gid];
    W_S[gid] = (bf16_t)(W_asrc[gid] + sub);
    W_D[gid] = (bf16_t)(W_adst[gid] - sub);
    W_amulb[gid]   = (bf16_t)W_amul[gid];
    W_poolb[gid]   = (bf16_t)W_pool[gid];
    W_pool2b[gid]  = (bf16_t)W_pool2[gid];
    W_selfb[gid]   = (bf16_t)W_self[gid];
    W_neighb[gid]  = (bf16_t)W_neigh[gid];
    W_neigh2b[gid] = (bf16_t)W_neigh2[gid];
    W_mlpb[gid]            = (bf16_t)W_mlp[gid];
    W_mlpb[DD * DD + gid]  = (bf16_t)W_mlp[DD * DD + gid];
    if (gid < DD) {
        b_e[gid]   = b_asub[gid] + b_amul[gid] + b_asrc[gid] + b_adst[gid];
        b_rst[gid] = b_self[gid] + b_neigh[gid] + b_neigh2[gid];
    }
}

// ---------------- one 16xDD GEMM tile (per wave), store bf16 ----------------
__device__ __forceinline__ void mm16_store(
    const bf16x8 a[4], const bf16_t* __restrict__ W,
    const float* __restrict__ bias, bool do_gelu,
    bf16_t* __restrict__ out, int nb, int n, int q)
{
#pragma unroll
    for (int t = 0; t < 8; t++) {
        f32x4 acc = {0.f, 0.f, 0.f, 0.f};
#pragma unroll
        for (int kb = 0; kb < 4; kb++) {
            bf16x8 b = *(const bf16x8*)(W + (t * 16 + n) * DD + kb * 32 + q * 8);
            acc = __builtin_amdgcn_mfma_f32_16x16x32_bf16(a[kb], b, acc, 0, 0, 0);
        }
        int ch = t * 16 + n;
        float bv = bias ? bias[ch] : 0.0f;
#pragma unroll
        for (int r = 0; r < 4; r++) {
            float v = acc[r] + bv;
            if (do_gelu) v = gelu_f(v);
            out[(size_t)(nb + q * 4 + r) * DD + ch] = (bf16_t)v;
        }
    }
}

// ---------------- per-node linears: S, D, h, h2 ----------------
__global__ __launch_bounds__(256) void node_linear_kernel(
    const bf16_t* __restrict__ fb,
    const bf16_t* __restrict__ W_S, const bf16_t* __restrict__ W_D,
    const bf16_t* __restrict__ W_pool, const float* __restrict__ b_pool,
    const bf16_t* __restrict__ W_pool2, const float* __restrict__ b_pool2,
    bf16_t* __restrict__ Sb, bf16_t* __restrict__ Db,
    bf16_t* __restrict__ hb, bf16_t* __restrict__ h2b)
{
    int wid = blockIdx.x * 4 + (threadIdx.x >> 6);
    if (wid >= NN / 16) return;
    int lane = threadIdx.x & 63, n = lane & 15, q = lane >> 4;
    int nb = wid * 16;
    bf16x8 a[4];
#pragma unroll
    for (int kb = 0; kb < 4; kb++)
        a[kb] = *(const bf16x8*)(fb + (size_t)(nb + n) * DD + kb * 32 + q * 8);
    mm16_store(a, W_S, nullptr, false, Sb, nb, n, q);
    mm16_store(a, W_D, nullptr, false, Db, nb, n, q);
    mm16_store(a, W_pool, b_pool, true, hb, nb, n, q);
    mm16_store(a, W_pool2, b_pool2, true, h2b, nb, n, q);
}

// ---------------- CSR build ----------------
__global__ __launch_bounds__(256) void hist_kernel(const int* __restrict__ dst, int* __restrict__ deg) {
    int e = blockIdx.x * 256 + threadIdx.x;
    if (e < NE) atomicAdd(&deg[dst[e]], 1);
}

__global__ __launch_bounds__(1024) void scan_kernel(const int* __restrict__ deg,
                                                    int* __restrict__ offsets,
                                                    int* __restrict__ cursor)
{
    __shared__ int part[1024];
    int t = threadIdx.x;
    const int CH = (NN + 1023) / 1024;  // 49
    int lo = t * CH, hi = lo + CH; if (hi > NN) hi = NN; if (lo > NN) lo = NN;
    int s = 0;
    for (int i = lo; i < hi; i++) s += deg[i];
    part[t] = s;
    __syncthreads();
    for (int d = 1; d < 1024; d <<= 1) {
        int v = (t >= d) ? part[t - d] : 0;
        __syncthreads();
        part[t] += v;
        __syncthreads();
    }
    int excl = (t > 0) ? part[t - 1] : 0;
    for (int i = lo; i < hi; i++) {
        offsets[i] = excl;
        cursor[i] = excl;
        excl += deg[i];
    }
}

__global__ __launch_bounds__(256) void scatter_kernel(
    const int* __restrict__ src, const int* __restrict__ dst,
    int* __restrict__ cursor, int* __restrict__ csr_eid, int* __restrict__ csr_src)
{
    int e = blockIdx.x * 256 + threadIdx.x;
    if (e < NE) {
        int d = dst[e];
        int pos = atomicAdd(&cursor[d], 1);
        csr_eid[pos] = e;
        csr_src[pos] = src[e];
    }
}

// ---------------- per-edge score (16 edges per wave) ----------------
__global__ __launch_bounds__(256) void edge_score_kernel(
    const bf16_t* __restrict__ fb, const int* __restrict__ src, const int* __restrict__ dst,
    const bf16_t* __restrict__ W_amul, const float* __restrict__ w_aout, const float* __restrict__ b_aout,
    const bf16_t* __restrict__ Sb, const bf16_t* __restrict__ Db, const float* __restrict__ b_e,
    float* __restrict__ scores)
{
    __shared__ __align__(16) float lds[4][16 * 132];
    int wave = threadIdx.x >> 6, lane = threadIdx.x & 63;
    int eb = (blockIdx.x * 4 + wave) * 16;  // exact: NE/16 == gridDim*4
    int m = lane & 15, q = lane >> 4;
    int s_m = src[eb + m], d_m = dst[eb + m];

    // A fragments: p = fs * fd (product in f32, rounded to bf16)
    bf16x8 a[4];
#pragma unroll
    for (int kb = 0; kb < 4; kb++) {
        bf16x8 fs = *(const bf16x8*)(fb + (size_t)s_m * DD + kb * 32 + q * 8);
        bf16x8 fd = *(const bf16x8*)(fb + (size_t)d_m * DD + kb * 32 + q * 8);
        bf16x8 p;
#pragma unroll
        for (int j = 0; j < 8; j++) p[j] = (bf16_t)((float)fs[j] * (float)fd[j]);
        a[kb] = p;
    }

    float* L = lds[wave];
#pragma unroll
    for (int t = 0; t < 8; t++) {
        f32x4 acc = {0.f, 0.f, 0.f, 0.f};
#pragma unroll
        for (int kb = 0; kb < 4; kb++) {
            bf16x8 b = *(const bf16x8*)(W_amul + (t * 16 + m) * DD + kb * 32 + q * 8);
            acc = __builtin_amdgcn_mfma_f32_16x16x32_bf16(a[kb], b, acc, 0, 0, 0);
        }
        // C layout: row(edge)=q*4+r, col(ch)=t*16+m  -> LDS[edge][ch], stride 132
#pragma unroll
        for (int r = 0; r < 4; r++) L[(q * 4 + r) * 132 + t * 16 + m] = acc[r];
    }
    __builtin_amdgcn_wave_barrier();  // order intra-wave LDS write->read

    int c1 = lane, c2 = lane + 64;
    float w1 = w_aout[c1], w2 = w_aout[c2];
    float be1 = b_e[c1], be2 = b_e[c2];
    float bout = b_aout[0];
#pragma unroll 4
    for (int e = 0; e < 16; e++) {
        int se = __shfl(s_m, e, 64);
        int de = __shfl(d_m, e, 64);
        float v1 = L[e * 132 + c1] + (float)Sb[(size_t)se * DD + c1] + (float)Db[(size_t)de * DD + c1] + be1;
        float v2 = L[e * 132 + c2] + (float)Sb[(size_t)se * DD + c2] + (float)Db[(size_t)de * DD + c2] + be2;
        float acc = gelu_f(v1) * w1 + gelu_f(v2) * w2;
#pragma unroll
        for (int off = 32; off >= 1; off >>= 1) acc += __shfl_xor(acc, off, 64);
        if (lane == 0) {
            float sc = acc + bout;
            scores[eb + e] = sc > 0.f ? sc : 0.2f * sc;
        }
    }
}

// ---------------- per-node aggregation over CSR ----------------
__global__ __launch_bounds__(256) void aggregate_kernel(
    const bf16_t* __restrict__ hb, const bf16_t* __restrict__ h2b, const float* __restrict__ scores,
    const int* __restrict__ offsets, const int* __restrict__ cursor_end,
    const int* __restrict__ csr_eid, const int* __restrict__ csr_src,
    bf16_t* __restrict__ neigh, bf16_t* __restrict__ neigh2)
{
    int wave = threadIdx.x >> 6, lane = threadIdx.x & 63;
    int v = blockIdx.x * 4 + wave;
    if (v >= NN) return;
    int off = offsets[v];
    int dg = cursor_end[v] - off;  // after scatter, cursor[v] == offsets[v] + deg[v]
    int c1 = lane, c2 = lane + 64;
    float mx1 = -INFINITY, mx2 = -INFINITY, s1 = 0.f, s2 = 0.f;
    for (int i = 0; i < dg; i++) {
        int e = csr_eid[off + i];
        int s = csr_src[off + i];
        float sc = scores[e];
        float a1 = sc * (float)hb[(size_t)s * DD + c1];
        float a2 = sc * (float)hb[(size_t)s * DD + c2];
        mx1 = fmaxf(mx1, a1);
        mx2 = fmaxf(mx2, a2);
        s1 += sc * (float)h2b[(size_t)s * DD + c1];
        s2 += sc * (float)h2b[(size_t)s * DD + c2];
    }
    float inv = 1.0f / (float)(dg > 1 ? dg : 1);
    neigh[(size_t)v * DD + c1] = (bf16_t)(dg > 0 ? mx1 : 0.0f);
    neigh[(size_t)v * DD + c2] = (bf16_t)(dg > 0 ? mx2 : 0.0f);
    neigh2[(size_t)v * DD + c1] = (bf16_t)(s1 * inv);
    neigh2[(size_t)v * DD + c2] = (bf16_t)(s2 * inv);
}

// ---------------- final: self+neigh+neigh2 linears, then 2 MLP layers ----------------
__global__ __launch_bounds__(256) void final_kernel(
    const bf16_t* __restrict__ fb, const bf16_t* __restrict__ neigh, const bf16_t* __restrict__ neigh2,
    const bf16_t* __restrict__ W_self, const bf16_t* __restrict__ W_neigh, const bf16_t* __restrict__ W_neigh2,
    const float* __restrict__ b_rst,
    const bf16_t* __restrict__ W_mlp, const float* __restrict__ b_mlp,
    float* __restrict__ out)
{
    __shared__ __align__(16) float lds[4][16 * 132];
    int wave = threadIdx.x >> 6;
    int wid = blockIdx.x * 4 + wave;
    if (wid >= NN / 16) return;
    int lane = threadIdx.x & 63, n = lane & 15, q = lane >> 4;
    int nb = wid * 16;
    float* L = lds[wave];

    bf16x8 af[4], an[4], am[4];
#pragma unroll
    for (int kb = 0; kb < 4; kb++) {
        size_t o = (size_t)(nb + n) * DD + kb * 32 + q * 8;
        af[kb] = *(const bf16x8*)(fb + o);
        an[kb] = *(const bf16x8*)(neigh + o);
        am[kb] = *(const bf16x8*)(neigh2 + o);
    }
    f32x4 rst[8];
#pragma unroll
    for (int t = 0; t < 8; t++) {
        f32x4 acc = {0.f, 0.f, 0.f, 0.f};
#pragma unroll
        for (int kb = 0; kb < 4; kb++) {
            int wo = (t * 16 + n) * DD + kb * 32 + q * 8;
            acc = __builtin_amdgcn_mfma_f32_16x16x32_bf16(af[kb], *(const bf16x8*)(W_self + wo), acc, 0, 0, 0);
            acc = __builtin_amdgcn_mfma_f32_16x16x32_bf16(an[kb], *(const bf16x8*)(W_neigh + wo), acc, 0, 0, 0);
            acc = __builtin_amdgcn_mfma_f32_16x16x32_bf16(am[kb], *(const bf16x8*)(W_neigh2 + wo), acc, 0, 0, 0);
        }
        float bv = b_rst[t * 16 + n];
#pragma unroll
        for (int r = 0; r < 4; r++) acc[r] += bv;
        rst[t] = acc;
    }

#pragma unroll
    for (int li = 0; li < 2; li++) {
        // gelu(rst) -> LDS row-major [node][ch], stride 132 floats
#pragma unroll
        for (int t = 0; t < 8; t++)
#pragma unroll
            for (int r = 0; r < 4; r++)
                L[(q * 4 + r) * 132 + t * 16 + n] = gelu_f(rst[t][r]);
        __builtin_amdgcn_wave_barrier();
        bf16x8 g[4];
#pragma unroll
        for (int kb = 0; kb < 4; kb++) {
            const f32x4* p = (const f32x4*)&L[n * 132 + kb * 32 + q * 8];
            f32x4 x0 = p[0], x1 = p[1];
            bf16x8 gg;
            gg[0] = (bf16_t)x0[0]; gg[1] = (bf16_t)x0[1]; gg[2] = (bf16_t)x0[2]; gg[3] = (bf16_t)x0[3];
            gg[4] = (bf16_t)x1[0]; gg[5] = (bf16_t)x1[1]; gg[6] = (bf16_t)x1[2]; gg[7] = (bf16_t)x1[3];
            g[kb] = gg;
        }
        __builtin_amdgcn_wave_barrier();
        const bf16_t* Wl = W_mlp + li * DD * DD;
#pragma unroll
        for (int t = 0; t < 8; t++) {
            f32x4 acc = {0.f, 0.f, 0.f, 0.f};
#pragma unroll
            for (int kb = 0; kb < 4; kb++) {
                bf16x8 b = *(const bf16x8*)(Wl + (t * 16 + n) * DD + kb * 32 + q * 8);
                acc = __builtin_amdgcn_mfma_f32_16x16x32_bf16(g[kb], b, acc, 0, 0, 0);
            }
            float bm = b_mlp[li * DD + t * 16 + n];
#pragma unroll
            for (int r = 0; r < 4; r++) rst[t][r] += acc[r] + bm;
        }
    }

#pragma unroll
    for (int t = 0; t < 8; t++)
#pragma unroll
        for (int r = 0; r < 4; r++)
            out[(size_t)(nb + q * 4 + r) * DD + t * 16 + n] = rst[t][r];
}

// ---------------- host launch ----------------
extern "C" void kernel_launch(void* const* d_in, const int* in_sizes, int n_in,
                              void* d_out, int out_size, void* d_ws, size_t ws_size,
                              hipStream_t stream)
{
    const float* feat    = (const float*)d_in[0];
    const int*   src     = (const int*)d_in[1];
    const int*   dst     = (const int*)d_in[2];
    const float* W_asrc  = (const float*)d_in[3],  *b_asrc  = (const float*)d_in[4];
    const float* W_adst  = (const float*)d_in[5],  *b_adst  = (const float*)d_in[6];
    const float* W_asub  = (const float*)d_in[7],  *b_asub  = (const float*)d_in[8];
    const float* W_amul  = (const float*)d_in[9],  *b_amul  = (const float*)d_in[10];
    const float* W_aout  = (const float*)d_in[11], *b_aout  = (const float*)d_in[12];
    const float* W_pool  = (const float*)d_in[13], *b_pool  = (const float*)d_in[14];
    const float* W_pool2 = (const float*)d_in[15], *b_pool2 = (const float*)d_in[16];
    const float* W_self  = (const float*)d_in[17], *b_self  = (const float*)d_in[18];
    const float* W_neigh = (const float*)d_in[19], *b_neigh = (const float*)d_in[20];
    const float* W_neigh2= (const float*)d_in[21], *b_neigh2= (const float*)d_in[22];
    const float* W_mlp   = (const float*)d_in[23], *b_mlp   = (const float*)d_in[24];
    float* out = (float*)d_out;

    char* w = (char*)d_ws;
    auto take = [&](size_t bytes) -> void* {
        void* p = (void*)w;
        w += (bytes + 255) & ~(size_t)255;
        return p;
    };
    bf16_t* fb      = (bf16_t*)take((size_t)NN * DD * sizeof(bf16_t));
    bf16_t* Sb      = (bf16_t*)take((size_t)NN * DD * sizeof(bf16_t));  // reused as neigh
    bf16_t* Db      = (bf16_t*)take((size_t)NN * DD * sizeof(bf16_t));  // reused as neigh2
    bf16_t* hb      = (bf16_t*)take((size_t)NN * DD * sizeof(bf16_t));
    bf16_t* h2b     = (bf16_t*)take((size_t)NN * DD * sizeof(bf16_t));
    float*  scores  = (float*)take((size_t)NE * sizeof(float));
    int*    deg     = (int*)take((size_t)NN * sizeof(int));
    int*    offsets = (int*)take((size_t)NN * sizeof(int));
    int*    cursor  = (int*)take((size_t)NN * sizeof(int));
    int*    csr_eid = (int*)take((size_t)NE * sizeof(int));
    int*    csr_src = (int*)take((size_t)NE * sizeof(int));
    bf16_t* W_S     = (bf16_t*)take((size_t)DD * DD * sizeof(bf16_t));
    bf16_t* W_D     = (bf16_t*)take((size_t)DD * DD * sizeof(bf16_t));
    bf16_t* W_amulb = (bf16_t*)take((size_t)DD * DD * sizeof(bf16_t));
    bf16_t* W_poolb = (bf16_t*)take((size_t)DD * DD * sizeof(bf16_t));
    bf16_t* W_pool2b= (bf16_t*)take((size_t)DD * DD * sizeof(bf16_t));
    bf16_t* W_selfb = (bf16_t*)take((size_t)DD * DD * sizeof(bf16_t));
    bf16_t* W_neighb= (bf16_t*)take((size_t)DD * DD * sizeof(bf16_t));
    bf16_t* W_neigh2b=(bf16_t*)take((size_t)DD * DD * sizeof(bf16_t));
    bf16_t* W_mlpb  = (bf16_t*)take((size_t)2 * DD * DD * sizeof(bf16_t));
    float*  b_e     = (float*)take((size_t)DD * sizeof(float));
    float*  b_rst   = (float*)take((size_t)DD * sizeof(float));
    // total ~74.6 MB

    hipMemsetAsync(deg, 0, (size_t)NN * sizeof(int), stream);

    convert_feat_kernel<<<NN * DD / 4 / 256, 256, 0, stream>>>(feat, fb);

    prep_kernel<<<DD * DD / 256, 256, 0, stream>>>(
        W_asrc, b_asrc, W_adst, b_adst, W_asub, b_asub, W_amul, b_amul,
        W_pool, W_pool2, W_self, b_self, W_neigh, b_neigh, W_neigh2, b_neigh2, W_mlp,
        W_S, W_D, W_amulb, W_poolb, W_pool2b, W_selfb, W_neighb, W_neigh2b, W_mlpb,
        b_e, b_rst);

    const int nwaves = NN / 16;                 // 3125
    const int ngrid = (nwaves + 3) / 4;         // 782
    node_linear_kernel<<<ngrid, 256, 0, stream>>>(
        fb, W_S, W_D, W_poolb, b_pool, W_pool2b, b_pool2, Sb, Db, hb, h2b);

    hist_kernel<<<(NE + 255) / 256, 256, 0, stream>>>(dst, deg);
    scan_kernel<<<1, 1024, 0, stream>>>(deg, offsets, cursor);
    scatter_kernel<<<(NE + 255) / 256, 256, 0, stream>>>(src, dst, cursor, csr_eid, csr_src);

    edge_score_kernel<<<NE / 64, 256, 0, stream>>>(
        fb, src, dst, W_amulb, W_aout, b_aout, Sb, Db, b_e, scores);

    aggregate_kernel<<<(NN + 3) / 4, 256, 0, stream>>>(
        hb, h2b, scores, offsets, cursor, csr_eid, csr_src, Sb /*neigh*/, Db /*neigh2*/);

    final_kernel<<<ngrid, 256, 0, stream>>>(
        fb, Sb /*neigh*/, Db /*neigh2*/, W_selfb, W_neighb, W_neigh2b, b_rst, W_mlpb, b_mlp, out);
}

// Round 3
// 717.660 us; speedup vs baseline: 1.3027x; 1.3027x over previous
//
#include <hip/hip_runtime.h>
#include <cstdint>
#include <cstddef>

#define NN 50000
#define NE 800000
#define DD 128

static_assert(NN % 16 == 0, "node tiles");
static_assert(NE % 16 == 0, "edge tiles");

typedef __bf16 bf16_t;
typedef bf16_t bf16x8 __attribute__((ext_vector_type(8)));
typedef bf16_t bf16x4 __attribute__((ext_vector_type(4)));
typedef bf16_t bf16x2 __attribute__((ext_vector_type(2)));
typedef float f32x4 __attribute__((ext_vector_type(4)));

__device__ __forceinline__ float gelu_f(float x) {
    return 0.5f * x * (1.0f + erff(x * 0.70710678118654752f));
}

// ---------------- feat f32 -> bf16 ----------------
__global__ __launch_bounds__(256) void convert_feat_kernel(
    const float* __restrict__ feat, bf16_t* __restrict__ fb)
{
    int i = blockIdx.x * 256 + threadIdx.x;  // quad index; NN*DD/4 = 1.6M exact
    f32x4 v = ((const f32x4*)feat)[i];
    bf16x4 o;
    o[0] = (bf16_t)v[0]; o[1] = (bf16_t)v[1]; o[2] = (bf16_t)v[2]; o[3] = (bf16_t)v[3];
    ((bf16x4*)fb)[i] = o;
}

// ---------------- prep: combine + convert weights, combine biases ----------------
__global__ __launch_bounds__(256) void prep_kernel(
    const float* __restrict__ W_asrc, const float* __restrict__ b_asrc,
    const float* __restrict__ W_adst, const float* __restrict__ b_adst,
    const float* __restrict__ W_asub, const float* __restrict__ b_asub,
    const float* __restrict__ W_amul, const float* __restrict__ b_amul,
    const float* __restrict__ W_pool, const float* __restrict__ W_pool2,
    const float* __restrict__ W_self, const float* __restrict__ b_self,
    const float* __restrict__ W_neigh, const float* __restrict__ b_neigh,
    const float* __restrict__ W_neigh2, const float* __restrict__ b_neigh2,
    const float* __restrict__ W_mlp,
    bf16_t* __restrict__ W_S, bf16_t* __restrict__ W_D, bf16_t* __restrict__ W_amulb,
    bf16_t* __restrict__ W_poolb, bf16_t* __restrict__ W_pool2b,
    bf16_t* __restrict__ W_selfb, bf16_t* __restrict__ W_neighb, bf16_t* __restrict__ W_neigh2b,
    bf16_t* __restrict__ W_mlpb,
    float* __restrict__ b_e, float* __restrict__ b_rst)
{
    int gid = blockIdx.x * 256 + threadIdx.x;  // 64 blocks * 256 = 16384 = DD*DD
    float sub = W_asub[gid];
    W_S[gid] = (bf16_t)(W_asrc[gid] + sub);
    W_D[gid] = (bf16_t)(W_adst[gid] - sub);
    W_amulb[gid]   = (bf16_t)W_amul[gid];
    W_poolb[gid]   = (bf16_t)W_pool[gid];
    W_pool2b[gid]  = (bf16_t)W_pool2[gid];
    W_selfb[gid]   = (bf16_t)W_self[gid];
    W_neighb[gid]  = (bf16_t)W_neigh[gid];
    W_neigh2b[gid] = (bf16_t)W_neigh2[gid];
    W_mlpb[gid]            = (bf16_t)W_mlp[gid];
    W_mlpb[DD * DD + gid]  = (bf16_t)W_mlp[DD * DD + gid];
    if (gid < DD) {
        b_e[gid]   = b_asub[gid] + b_amul[gid] + b_asrc[gid] + b_adst[gid];
        b_rst[gid] = b_self[gid] + b_neigh[gid] + b_neigh2[gid];
    }
}

// ---------------- one 16xDD GEMM tile (per wave), store bf16 row-major ----------------
__device__ __forceinline__ void mm16_store(
    const bf16x8 a[4], const bf16_t* __restrict__ W,
    bf16_t* __restrict__ out, int nb, int n, int q)
{
#pragma unroll
    for (int t = 0; t < 8; t++) {
        f32x4 acc = {0.f, 0.f, 0.f, 0.f};
#pragma unroll
        for (int kb = 0; kb < 4; kb++) {
            bf16x8 b = *(const bf16x8*)(W + (t * 16 + n) * DD + kb * 32 + q * 8);
            acc = __builtin_amdgcn_mfma_f32_16x16x32_bf16(a[kb], b, acc, 0, 0, 0);
        }
        int ch = t * 16 + n;
#pragma unroll
        for (int r = 0; r < 4; r++)
            out[(size_t)(nb + q * 4 + r) * DD + ch] = (bf16_t)acc[r];
    }
}

// same, but gelu + store interleaved into hh[node][256]: hb ch -> (ch/2)*4+(ch&1), h2b -> +2
__device__ __forceinline__ void mm16_store_ilv(
    const bf16x8 a[4], const bf16_t* __restrict__ W, const float* __restrict__ bias,
    bf16_t* __restrict__ hh, int nb, int n, int q, int sub)
{
#pragma unroll
    for (int t = 0; t < 8; t++) {
        f32x4 acc = {0.f, 0.f, 0.f, 0.f};
#pragma unroll
        for (int kb = 0; kb < 4; kb++) {
            bf16x8 b = *(const bf16x8*)(W + (t * 16 + n) * DD + kb * 32 + q * 8);
            acc = __builtin_amdgcn_mfma_f32_16x16x32_bf16(a[kb], b, acc, 0, 0, 0);
        }
        int ch = t * 16 + n;
        int pos = ((ch >> 1) << 2) + (ch & 1) + sub;
        float bv = bias[ch];
#pragma unroll
        for (int r = 0; r < 4; r++)
            hh[(size_t)(nb + q * 4 + r) * 256 + pos] = (bf16_t)gelu_f(acc[r] + bv);
    }
}

// ---------------- per-node linears: S, D, h/h2 (interleaved) ----------------
__global__ __launch_bounds__(256) void node_linear_kernel(
    const bf16_t* __restrict__ fb,
    const bf16_t* __restrict__ W_S, const bf16_t* __restrict__ W_D,
    const bf16_t* __restrict__ W_pool, const float* __restrict__ b_pool,
    const bf16_t* __restrict__ W_pool2, const float* __restrict__ b_pool2,
    bf16_t* __restrict__ Sb, bf16_t* __restrict__ Db, bf16_t* __restrict__ hh)
{
    int wid = blockIdx.x * 4 + (threadIdx.x >> 6);
    if (wid >= NN / 16) return;
    int lane = threadIdx.x & 63, n = lane & 15, q = lane >> 4;
    int nb = wid * 16;
    bf16x8 a[4];
#pragma unroll
    for (int kb = 0; kb < 4; kb++)
        a[kb] = *(const bf16x8*)(fb + (size_t)(nb + n) * DD + kb * 32 + q * 8);
    mm16_store(a, W_S, Sb, nb, n, q);
    mm16_store(a, W_D, Db, nb, n, q);
    mm16_store_ilv(a, W_pool, b_pool, hh, nb, n, q, 0);
    mm16_store_ilv(a, W_pool2, b_pool2, hh, nb, n, q, 2);
}

// ---------------- CSR build ----------------
__global__ __launch_bounds__(256) void hist_kernel(const int* __restrict__ dst, int* __restrict__ deg) {
    int e = blockIdx.x * 256 + threadIdx.x;
    if (e < NE) atomicAdd(&deg[dst[e]], 1);
}

#define SCAN_NB ((NN + 255) / 256)  // 196

__global__ __launch_bounds__(256) void scan1_kernel(const int* __restrict__ deg,
                                                    int* __restrict__ offsets, int* __restrict__ bsum)
{
    __shared__ int tmp[256];
    int t = threadIdx.x, g = blockIdx.x * 256 + t;
    int v = (g < NN) ? deg[g] : 0;
    tmp[t] = v;
    __syncthreads();
#pragma unroll
    for (int d = 1; d < 256; d <<= 1) {
        int x = (t >= d) ? tmp[t - d] : 0;
        __syncthreads();
        tmp[t] += x;
        __syncthreads();
    }
    if (g < NN) offsets[g] = tmp[t] - v;  // local exclusive
    if (t == 255) bsum[blockIdx.x] = tmp[255];
}

__global__ __launch_bounds__(256) void scan2_kernel(const int* __restrict__ bsum, int* __restrict__ bbase)
{
    __shared__ int tmp[256];
    int t = threadIdx.x;
    int v = (t < SCAN_NB) ? bsum[t] : 0;
    tmp[t] = v;
    __syncthreads();
#pragma unroll
    for (int d = 1; d < 256; d <<= 1) {
        int x = (t >= d) ? tmp[t - d] : 0;
        __syncthreads();
        tmp[t] += x;
        __syncthreads();
    }
    if (t < SCAN_NB) bbase[t] = tmp[t] - v;
}

__global__ __launch_bounds__(256) void scan3_kernel(const int* __restrict__ bbase,
                                                    int* __restrict__ offsets, int* __restrict__ cursor)
{
    int g = blockIdx.x * 256 + threadIdx.x;
    if (g < NN) {
        int o = offsets[g] + bbase[blockIdx.x];
        offsets[g] = o;
        cursor[g] = o;
    }
}

// scatter AFTER edge_score: pack {src, score-bits} per CSR slot
__global__ __launch_bounds__(256) void scatter_kernel(
    const int* __restrict__ src, const int* __restrict__ dst, const float* __restrict__ scores,
    int* __restrict__ cursor, int2* __restrict__ csr)
{
    int e = blockIdx.x * 256 + threadIdx.x;
    if (e < NE) {
        int d = dst[e];
        int pos = atomicAdd(&cursor[d], 1);
        int2 pk;
        pk.x = src[e];
        pk.y = __float_as_int(scores[e]);
        csr[pos] = pk;
    }
}

// ---------------- per-edge score (16 edges per wave) ----------------
__global__ __launch_bounds__(256) void edge_score_kernel(
    const bf16_t* __restrict__ fb, const int* __restrict__ src, const int* __restrict__ dst,
    const bf16_t* __restrict__ W_amul, const float* __restrict__ w_aout, const float* __restrict__ b_aout,
    const bf16_t* __restrict__ Sb, const bf16_t* __restrict__ Db, const float* __restrict__ b_e,
    float* __restrict__ scores)
{
    __shared__ __align__(16) float lds[4][16 * 132];
    int wave = threadIdx.x >> 6, lane = threadIdx.x & 63;
    int eb = (blockIdx.x * 4 + wave) * 16;  // exact: NE/16 == gridDim*4
    int m = lane & 15, q = lane >> 4;
    int s_m = src[eb + m], d_m = dst[eb + m];

    const bf16_t* fsp = fb + (size_t)s_m * DD;
    const bf16_t* fdp = fb + (size_t)d_m * DD;
    const bf16_t* Ssp = Sb + (size_t)s_m * DD;
    const bf16_t* Ddp = Db + (size_t)d_m * DD;

    // batch-issue all gathers (16x 16B per lane)
    bf16x8 fs[4], fd[4], Sf[4], Df[4];
#pragma unroll
    for (int kb = 0; kb < 4; kb++) {
        int o = kb * 32 + q * 8;
        fs[kb] = *(const bf16x8*)(fsp + o);
        fd[kb] = *(const bf16x8*)(fdp + o);
        Sf[kb] = *(const bf16x8*)(Ssp + o);
        Df[kb] = *(const bf16x8*)(Ddp + o);
    }
    // p = fs*fd (f32 mul, round to bf16)
    bf16x8 a[4];
#pragma unroll
    for (int kb = 0; kb < 4; kb++) {
        bf16x8 p;
#pragma unroll
        for (int j = 0; j < 8; j++) p[j] = (bf16_t)((float)fs[kb][j] * (float)fd[kb][j]);
        a[kb] = p;
    }

    float* L = lds[wave];
#pragma unroll
    for (int t = 0; t < 8; t++) {
        f32x4 acc = {0.f, 0.f, 0.f, 0.f};
#pragma unroll
        for (int kb = 0; kb < 4; kb++) {
            bf16x8 b = *(const bf16x8*)(W_amul + (t * 16 + m) * DD + kb * 32 + q * 8);
            acc = __builtin_amdgcn_mfma_f32_16x16x32_bf16(a[kb], b, acc, 0, 0, 0);
        }
        // C layout: row(edge)=q*4+r, col(ch)=t*16+m -> LDS[edge][ch], stride 132
#pragma unroll
        for (int r = 0; r < 4; r++) L[(q * 4 + r) * 132 + t * 16 + m] = acc[r];
    }
    __builtin_amdgcn_wave_barrier();  // order intra-wave LDS write->read

    // tail in A-fragment layout: lane handles edge m, channels kb*32+q*8+j
    float accv = 0.f;
    const float* Lrow = L + m * 132;
#pragma unroll
    for (int kb = 0; kb < 4; kb++) {
        int o = kb * 32 + q * 8;
        f32x4 p0 = *(const f32x4*)(Lrow + o);
        f32x4 p1 = *(const f32x4*)(Lrow + o + 4);
        f32x4 be0 = *(const f32x4*)(b_e + o);
        f32x4 be1 = *(const f32x4*)(b_e + o + 4);
        f32x4 w0 = *(const f32x4*)(w_aout + o);
        f32x4 w1 = *(const f32x4*)(w_aout + o + 4);
#pragma unroll
        for (int j = 0; j < 4; j++) {
            float v0 = p0[j] + (float)Sf[kb][j] + (float)Df[kb][j] + be0[j];
            float v1 = p1[j] + (float)Sf[kb][j + 4] + (float)Df[kb][j + 4] + be1[j];
            accv = fmaf(gelu_f(v0), w0[j], accv);
            accv = fmaf(gelu_f(v1), w1[j], accv);
        }
    }
    accv += __shfl_xor(accv, 16, 64);
    accv += __shfl_xor(accv, 32, 64);
    if (q == 0) {
        float sc = accv + b_aout[0];
        scores[eb + m] = sc > 0.f ? sc : 0.2f * sc;
    }
}

// ---------------- per-node aggregation over CSR ----------------
__global__ __launch_bounds__(256) void aggregate_kernel(
    const bf16_t* __restrict__ hh,
    const int* __restrict__ offsets, const int* __restrict__ cursor_end,
    const int2* __restrict__ csr,
    bf16_t* __restrict__ neigh, bf16_t* __restrict__ neigh2)
{
    int wave = threadIdx.x >> 6, lane = threadIdx.x & 63;
    int v = blockIdx.x * 4 + wave;
    if (v >= NN) return;
    int off = offsets[v];
    int dg = cursor_end[v] - off;  // cursor[v] == offsets[v] + deg[v] after scatter
    float mx0 = -INFINITY, mx1 = -INFINITY, s0 = 0.f, s1 = 0.f;
    for (int base = 0; base < dg; base += 64) {
        int cnt = dg - base; if (cnt > 64) cnt = 64;
        int s_l = 0; float sc_l = 0.f;
        if (lane < cnt) {
            int2 pk = csr[off + base + lane];
            s_l = pk.x;
            sc_l = __int_as_float(pk.y);
        }
#pragma unroll 4
        for (int i = 0; i < cnt; i++) {
            int s = __shfl(s_l, i, 64);
            float sc = __shfl(sc_l, i, 64);
            bf16x4 hv = *(const bf16x4*)(hh + (size_t)s * 256 + 4 * lane);
            mx0 = fmaxf(mx0, sc * (float)hv[0]);
            mx1 = fmaxf(mx1, sc * (float)hv[1]);
            s0 = fmaf(sc, (float)hv[2], s0);
            s1 = fmaf(sc, (float)hv[3], s1);
        }
    }
    float inv = 1.0f / (float)(dg > 1 ? dg : 1);
    bf16x2 n1, n2;
    n1[0] = (bf16_t)(dg > 0 ? mx0 : 0.0f);
    n1[1] = (bf16_t)(dg > 0 ? mx1 : 0.0f);
    n2[0] = (bf16_t)(s0 * inv);
    n2[1] = (bf16_t)(s1 * inv);
    *(bf16x2*)(neigh + (size_t)v * DD + 2 * lane) = n1;
    *(bf16x2*)(neigh2 + (size_t)v * DD + 2 * lane) = n2;
}

// ---------------- final: self+neigh+neigh2 linears, then 2 MLP layers ----------------
__global__ __launch_bounds__(256) void final_kernel(
    const bf16_t* __restrict__ fb, const bf16_t* __restrict__ neigh, const bf16_t* __restrict__ neigh2,
    const bf16_t* __restrict__ W_self, const bf16_t* __restrict__ W_neigh, const bf16_t* __restrict__ W_neigh2,
    const float* __restrict__ b_rst,
    const bf16_t* __restrict__ W_mlp, const float* __restrict__ b_mlp,
    float* __restrict__ out)
{
    __shared__ __align__(16) float lds[4][16 * 132];
    int wave = threadIdx.x >> 6;
    int wid = blockIdx.x * 4 + wave;
    if (wid >= NN / 16) return;
    int lane = threadIdx.x & 63, n = lane & 15, q = lane >> 4;
    int nb = wid * 16;
    float* L = lds[wave];

    bf16x8 af[4], an[4], am[4];
#pragma unroll
    for (int kb = 0; kb < 4; kb++) {
        size_t o = (size_t)(nb + n) * DD + kb * 32 + q * 8;
        af[kb] = *(const bf16x8*)(fb + o);
        an[kb] = *(const bf16x8*)(neigh + o);
        am[kb] = *(const bf16x8*)(neigh2 + o);
    }
    f32x4 rst[8];
#pragma unroll
    for (int t = 0; t < 8; t++) {
        f32x4 acc = {0.f, 0.f, 0.f, 0.f};
#pragma unroll
        for (int kb = 0; kb < 4; kb++) {
            int wo = (t * 16 + n) * DD + kb * 32 + q * 8;
            acc = __builtin_amdgcn_mfma_f32_16x16x32_bf16(af[kb], *(const bf16x8*)(W_self + wo), acc, 0, 0, 0);
            acc = __builtin_amdgcn_mfma_f32_16x16x32_bf16(an[kb], *(const bf16x8*)(W_neigh + wo), acc, 0, 0, 0);
            acc = __builtin_amdgcn_mfma_f32_16x16x32_bf16(am[kb], *(const bf16x8*)(W_neigh2 + wo), acc, 0, 0, 0);
        }
        float bv = b_rst[t * 16 + n];
#pragma unroll
        for (int r = 0; r < 4; r++) acc[r] += bv;
        rst[t] = acc;
    }

#pragma unroll
    for (int li = 0; li < 2; li++) {
#pragma unroll
        for (int t = 0; t < 8; t++)
#pragma unroll
            for (int r = 0; r < 4; r++)
                L[(q * 4 + r) * 132 + t * 16 + n] = gelu_f(rst[t][r]);
        __builtin_amdgcn_wave_barrier();
        bf16x8 g[4];
#pragma unroll
        for (int kb = 0; kb < 4; kb++) {
            const f32x4* p = (const f32x4*)&L[n * 132 + kb * 32 + q * 8];
            f32x4 x0 = p[0], x1 = p[1];
            bf16x8 gg;
            gg[0] = (bf16_t)x0[0]; gg[1] = (bf16_t)x0[1]; gg[2] = (bf16_t)x0[2]; gg[3] = (bf16_t)x0[3];
            gg[4] = (bf16_t)x1[0]; gg[5] = (bf16_t)x1[1]; gg[6] = (bf16_t)x1[2]; gg[7] = (bf16_t)x1[3];
            g[kb] = gg;
        }
        __builtin_amdgcn_wave_barrier();
        const bf16_t* Wl = W_mlp + li * DD * DD;
#pragma unroll
        for (int t = 0; t < 8; t++) {
            f32x4 acc = {0.f, 0.f, 0.f, 0.f};
#pragma unroll
            for (int kb = 0; kb < 4; kb++) {
                bf16x8 b = *(const bf16x8*)(Wl + (t * 16 + n) * DD + kb * 32 + q * 8);
                acc = __builtin_amdgcn_mfma_f32_16x16x32_bf16(g[kb], b, acc, 0, 0, 0);
            }
            float bm = b_mlp[li * DD + t * 16 + n];
#pragma unroll
            for (int r = 0; r < 4; r++) rst[t][r] += acc[r] + bm;
        }
    }

#pragma unroll
    for (int t = 0; t < 8; t++)
#pragma unroll
        for (int r = 0; r < 4; r++)
            out[(size_t)(nb + q * 4 + r) * DD + t * 16 + n] = rst[t][r];
}

// ---------------- host launch ----------------
extern "C" void kernel_launch(void* const* d_in, const int* in_sizes, int n_in,
                              void* d_out, int out_size, void* d_ws, size_t ws_size,
                              hipStream_t stream)
{
    const float* feat    = (const float*)d_in[0];
    const int*   src     = (const int*)d_in[1];
    const int*   dst     = (const int*)d_in[2];
    const float* W_asrc  = (const float*)d_in[3],  *b_asrc  = (const float*)d_in[4];
    const float* W_adst  = (const float*)d_in[5],  *b_adst  = (const float*)d_in[6];
    const float* W_asub  = (const float*)d_in[7],  *b_asub  = (const float*)d_in[8];
    const float* W_amul  = (const float*)d_in[9],  *b_amul  = (const float*)d_in[10];
    const float* W_aout  = (const float*)d_in[11], *b_aout  = (const float*)d_in[12];
    const float* W_pool  = (const float*)d_in[13], *b_pool  = (const float*)d_in[14];
    const float* W_pool2 = (const float*)d_in[15], *b_pool2 = (const float*)d_in[16];
    const float* W_self  = (const float*)d_in[17], *b_self  = (const float*)d_in[18];
    const float* W_neigh = (const float*)d_in[19], *b_neigh = (const float*)d_in[20];
    const float* W_neigh2= (const float*)d_in[21], *b_neigh2= (const float*)d_in[22];
    const float* W_mlp   = (const float*)d_in[23], *b_mlp   = (const float*)d_in[24];
    float* out = (float*)d_out;

    char* w = (char*)d_ws;
    auto take = [&](size_t bytes) -> void* {
        void* p = (void*)w;
        w += (bytes + 255) & ~(size_t)255;
        return p;
    };
    bf16_t* fb      = (bf16_t*)take((size_t)NN * DD * sizeof(bf16_t));
    bf16_t* Sb      = (bf16_t*)take((size_t)NN * DD * sizeof(bf16_t));  // reused as neigh
    bf16_t* Db      = (bf16_t*)take((size_t)NN * DD * sizeof(bf16_t));  // reused as neigh2
    bf16_t* hh      = (bf16_t*)take((size_t)NN * 256 * sizeof(bf16_t)); // h/h2 interleaved
    float*  scores  = (float*)take((size_t)NE * sizeof(float));
    int*    deg     = (int*)take((size_t)NN * sizeof(int));
    int*    offsets = (int*)take((size_t)NN * sizeof(int));
    int*    cursor  = (int*)take((size_t)NN * sizeof(int));
    int2*   csr     = (int2*)take((size_t)NE * sizeof(int2));
    int*    bsum    = (int*)take(256 * sizeof(int));
    int*    bbase   = (int*)take(256 * sizeof(int));
    bf16_t* W_S     = (bf16_t*)take((size_t)DD * DD * sizeof(bf16_t));
    bf16_t* W_D     = (bf16_t*)take((size_t)DD * DD * sizeof(bf16_t));
    bf16_t* W_amulb = (bf16_t*)take((size_t)DD * DD * sizeof(bf16_t));
    bf16_t* W_poolb = (bf16_t*)take((size_t)DD * DD * sizeof(bf16_t));
    bf16_t* W_pool2b= (bf16_t*)take((size_t)DD * DD * sizeof(bf16_t));
    bf16_t* W_selfb = (bf16_t*)take((size_t)DD * DD * sizeof(bf16_t));
    bf16_t* W_neighb= (bf16_t*)take((size_t)DD * DD * sizeof(bf16_t));
    bf16_t* W_neigh2b=(bf16_t*)take((size_t)DD * DD * sizeof(bf16_t));
    bf16_t* W_mlpb  = (bf16_t*)take((size_t)2 * DD * DD * sizeof(bf16_t));
    float*  b_e     = (float*)take((size_t)DD * sizeof(float));
    float*  b_rst   = (float*)take((size_t)DD * sizeof(float));

    hipMemsetAsync(deg, 0, (size_t)NN * sizeof(int), stream);

    convert_feat_kernel<<<NN * DD / 4 / 256, 256, 0, stream>>>(feat, fb);

    prep_kernel<<<DD * DD / 256, 256, 0, stream>>>(
        W_asrc, b_asrc, W_adst, b_adst, W_asub, b_asub, W_amul, b_amul,
        W_pool, W_pool2, W_self, b_self, W_neigh, b_neigh, W_neigh2, b_neigh2, W_mlp,
        W_S, W_D, W_amulb, W_poolb, W_pool2b, W_selfb, W_neighb, W_neigh2b, W_mlpb,
        b_e, b_rst);

    const int nwaves = NN / 16;                 // 3125
    const int ngrid = (nwaves + 3) / 4;         // 782
    node_linear_kernel<<<ngrid, 256, 0, stream>>>(
        fb, W_S, W_D, W_poolb, b_pool, W_pool2b, b_pool2, Sb, Db, hh);

    hist_kernel<<<(NE + 255) / 256, 256, 0, stream>>>(dst, deg);
    scan1_kernel<<<SCAN_NB, 256, 0, stream>>>(deg, offsets, bsum);
    scan2_kernel<<<1, 256, 0, stream>>>(bsum, bbase);
    scan3_kernel<<<SCAN_NB, 256, 0, stream>>>(bbase, offsets, cursor);

    edge_score_kernel<<<NE / 64, 256, 0, stream>>>(
        fb, src, dst, W_amulb, W_aout, b_aout, Sb, Db, b_e, scores);

    scatter_kernel<<<(NE + 255) / 256, 256, 0, stream>>>(src, dst, scores, cursor, csr);

    aggregate_kernel<<<(NN + 3) / 4, 256, 0, stream>>>(
        hh, offsets, cursor, csr, Sb /*neigh*/, Db /*neigh2*/);

    final_kernel<<<ngrid, 256, 0, stream>>>(
        fb, Sb /*neigh*/, Db /*neigh2*/, W_selfb, W_neighb, W_neigh2b, b_rst, W_mlpb, b_mlp, out);
}